// Round 20
// baseline (175.327 us; speedup 1.0000x reference)
//
#include <hip/hip_runtime.h>
#include <hip/hip_bf16.h>
#include <math.h>

#define NN 50000
#define DD 128
#define EE 800000

static constexpr float BN_EPS = 1e-3f;

typedef __attribute__((ext_vector_type(8))) short bf16x8;
typedef __attribute__((ext_vector_type(4))) float f32x4;

#define MFMA16(a, b, c) __builtin_amdgcn_mfma_f32_16x16x32_bf16((a), (b), (c), 0, 0, 0)

// fast exact-grade GELU: Abramowitz-Stegun 7.1.26 erf (abs err 1.5e-7)
__device__ __forceinline__ float gelu_f(float x) {
    float ax = fabsf(x) * 0.7071067811865475f;
    float t = __builtin_amdgcn_rcpf(fmaf(0.3275911f, ax, 1.0f));
    float p = t * fmaf(t, fmaf(t, fmaf(t, fmaf(t, 1.061405429f, -1.453152027f),
                                       1.421413741f), -0.284496736f), 0.254829592f);
    float e = __expf(-ax * ax);
    float er = fmaf(-p, e, 1.0f);        // erf(|x|/sqrt2) for ax>=0
    float s = copysignf(er, x);
    return 0.5f * x * (1.0f + s);
}

__device__ __forceinline__ ushort f2bf_rn(float f) {
    uint u = __float_as_uint(f);
    return (ushort)((u + 0x7FFFu + ((u >> 16) & 1u)) >> 16);
}
__device__ __forceinline__ float bf2f(ushort h) {
    return __uint_as_float(((uint)h) << 16);
}

// packed pair f32->bf16 RNE (compiler emits v_cvt_pk_bf16_f32); low16=a, high16=b
__device__ __forceinline__ uint pk2(float a, float b) {
    __hip_bfloat162 t = __float22bfloat162_rn(make_float2(a, b));
    uint r;
    __builtin_memcpy(&r, &t, 4);
    return r;
}

// split f32x8 -> bf16 hi + bf16 lo fragments (f ~= hi + lo, |resid| ~ 2^-17|f|)
__device__ __forceinline__ void cvt_hilo(float4 x0, float4 x1, bf16x8& h, bf16x8& l) {
    float f[8] = {x0.x, x0.y, x0.z, x0.w, x1.x, x1.y, x1.z, x1.w};
    union U { uint u[4]; bf16x8 v; } uh, ul;
    #pragma unroll
    for (int j = 0; j < 4; ++j) {
        uint p = pk2(f[2 * j], f[2 * j + 1]);
        uh.u[j] = p;
        float h0 = __uint_as_float(p << 16);
        float h1 = __uint_as_float(p & 0xFFFF0000u);
        ul.u[j] = pk2(f[2 * j] - h0, f[2 * j + 1] - h1);
    }
    h = uh.v;
    l = ul.v;
}

// ---------------- fused weight-prep kernels ----------------
__device__ __forceinline__ void pack_one(const float* __restrict__ W, const float* __restrict__ g,
                                         const float* __restrict__ v, ushort* __restrict__ hi,
                                         ushort* __restrict__ lo, int K, int idx) {
    int k = idx >> 7, col = idx & 127;
    float s = g[k] * rsqrtf(v[k] + BN_EPS);
    float f = s * W[idx];
    int S = K >> 5;
    int st = k >> 5, gq = (k >> 3) & 3, j = k & 7;
    int c = col >> 4, ln = (gq << 4) | (col & 15);
    int o = ((c * S + st) * 64 + ln) * 8 + j;
    ushort hb = f2bf_rn(f);
    hi[o] = hb;
    lo[o] = f2bf_rn(f - bf2f(hb));
}

__global__ void pack_all(
    const float* __restrict__ w1, const float* __restrict__ g1, const float* __restrict__ v1,
    ushort* __restrict__ W1h, ushort* __restrict__ W1l,
    const float* __restrict__ w2, const float* __restrict__ g2, const float* __restrict__ v2,
    ushort* __restrict__ W2h, ushort* __restrict__ W2l,
    const float* __restrict__ u1, const float* __restrict__ g3, const float* __restrict__ v3,
    ushort* __restrict__ U1h, ushort* __restrict__ U1l,
    const float* __restrict__ u2, const float* __restrict__ g4, const float* __restrict__ v4,
    ushort* __restrict__ U2h, ushort* __restrict__ U2l)
{
    int idx = blockIdx.x * 256 + threadIdx.x;       // 0..81919
    if (idx < 16384)       pack_one(w1, g1, v1, W1h, W1l, 128, idx);
    else if (idx < 32768)  pack_one(w2, g2, v2, W2h, W2l, 128, idx - 16384);
    else if (idx < 65536)  pack_one(u1, g3, v3, U1h, U1l, 256, idx - 32768);
    else                   pack_one(u2, g4, v4, U2h, U2l, 128, idx - 65536);
}

__global__ void init_bias(const float* __restrict__ b1, const float* __restrict__ b2,
                          const float* __restrict__ ub1, const float* __restrict__ ub2,
                          float* __restrict__ B1f, float* __restrict__ B2f,
                          float* __restrict__ C1f, float* __restrict__ C2f) {
    int t = threadIdx.x;  // 128
    B1f[t] = b1[t]; B2f[t] = b2[t]; C1f[t] = ub1[t]; C2f[t] = ub2[t];
}

// fused BN-bias fold (also zeroes cnt4[NN*4]+spillCnt for the fill pass downstream).
__global__ __launch_bounds__(256) void fold_all(
    const float* __restrict__ w1, const float* __restrict__ g1, const float* __restrict__ b1,
    const float* __restrict__ m1, const float* __restrict__ v1, float* __restrict__ B1f,
    const float* __restrict__ w2, const float* __restrict__ g2, const float* __restrict__ b2,
    const float* __restrict__ m2, const float* __restrict__ v2, float* __restrict__ B2f,
    const float* __restrict__ u1, const float* __restrict__ g3, const float* __restrict__ b3,
    const float* __restrict__ m3, const float* __restrict__ v3, float* __restrict__ C1f,
    const float* __restrict__ u2, const float* __restrict__ g4, const float* __restrict__ b4,
    const float* __restrict__ m4, const float* __restrict__ v4, float* __restrict__ C2f,
    int* __restrict__ cnt4, int* __restrict__ spillCnt)
{
    for (int i = blockIdx.x * 256 + threadIdx.x; i < NN * 4 + 1; i += 20 * 256) {
        if (i < NN * 4) cnt4[i] = 0; else spillCnt[0] = 0;
    }

    const int rs = blockIdx.x * 32;
    const float *W, *g, *bb, *m, *v;
    float* bf;
    int k0;
    if (rs < 128)      { W = w1; g = g1; bb = b1; m = m1; v = v1; bf = B1f; k0 = rs; }
    else if (rs < 256) { W = w2; g = g2; bb = b2; m = m2; v = v2; bf = B2f; k0 = rs - 128; }
    else if (rs < 512) { W = u1; g = g3; bb = b3; m = m3; v = v3; bf = C1f; k0 = rs - 256; }
    else               { W = u2; g = g4; bb = b4; m = m4; v = v4; bf = C2f; k0 = rs - 512; }

    const int t = threadIdx.x, j = t & 127, h = t >> 7;
    float acc = 0.f;
    #pragma unroll
    for (int kk = 0; kk < 16; ++kk) {
        int k = k0 + h * 16 + kk;
        float s = g[k] * rsqrtf(v[k] + BN_EPS);
        float tt = bb[k] - m[k] * s;
        acc = fmaf(tt, W[k * DD + j], acc);
    }
    __shared__ float S[256];
    S[t] = acc;
    __syncthreads();
    if (h == 0) atomicAdd(&bf[j], S[j] + S[128 + j]);
}

#define YLD 136
#define SECN 4             // nbr sections (msgN slice 3.2 MB < 4 MB per-XCD L2)
#define SECSZ 12500        // NN / SECN
#define SEC_CAP 12         // per (dst,sec) capacity; Poisson(4) P(>12)~2e-4 -> spill
#define BSTR (SECN * SEC_CAP)  // 48 ints per dst
#define SPILL_CAP 100000
#define NCHUNK 400
#define CHSZ (EE / NCHUNK) // 2000
#define PSZ 6250           // NN / 8 (dst partitions for fill XCD affinity)
#define FILLB (NCHUNK * 8) // 3200 fill blocks (first -> bid&7 = XCD partition)

// ---------------- fused kernel A: fill_bucket (memory/atomics) || prep FFN (MFMA) ------
__global__ __launch_bounds__(512, 4) void prep_fill(
    const float* __restrict__ reps, const int* __restrict__ edges,
    const ushort* __restrict__ W1h, const ushort* __restrict__ W1l, const float* __restrict__ B1,
    const ushort* __restrict__ W2h, const ushort* __restrict__ W2l, const float* __restrict__ B2,
    ushort* __restrict__ msgN,
    int* __restrict__ cnt4, int* __restrict__ spillCnt,
    int* __restrict__ spill, int* __restrict__ bucket)
{
    __shared__ ushort Yh[128 * YLD];

    if (blockIdx.x < FILLB) {
        const int part = blockIdx.x & 7;
        const int ch   = blockIdx.x >> 3;
        const int lo = part * PSZ, hi2 = lo + PSZ;
        const int base = ch * CHSZ;
        for (int i = threadIdx.x; i < CHSZ; i += 512) {
            int e = base + i;
            int d = edges[e];
            if (d >= lo && d < hi2) {
                int nb = edges[EE + e];
                int sec = nb / SECSZ;                     // nbr section
                int s = atomicAdd(&cnt4[d * SECN + sec], 1);
                if (s < SEC_CAP) bucket[d * BSTR + sec * SEC_CAP + s] = e;
                else { int sl = atomicAdd(spillCnt, 1); if (sl < SPILL_CAP) spill[sl] = e; }
            }
        }
        return;
    }

    const int pb = blockIdx.x - FILLB;
    if (pb >= 391) return;
    const int t = threadIdx.x;
    const int w = t >> 6, l = t & 63, lg = l >> 4, lr = l & 15;
    const int n0 = pb * 128;
    int n = n0 + w * 16 + lr;
    int nc = n < NN ? n : NN - 1;
    const float* src = reps + (size_t)nc * DD;

    float b1v[8], b2v[8];
    #pragma unroll
    for (int c = 0; c < 8; ++c) { b1v[c] = B1[c * 16 + lr]; b2v[c] = B2[c * 16 + lr]; }

    f32x4 acc[8];
    #pragma unroll
    for (int c = 0; c < 8; ++c) acc[c] = (f32x4)(0.f);

    #pragma unroll
    for (int s = 0; s < 4; ++s) {
        float4 x0 = *reinterpret_cast<const float4*>(src + s * 32 + lg * 8);
        float4 x1 = *reinterpret_cast<const float4*>(src + s * 32 + lg * 8 + 4);
        bf16x8 ah, al;
        cvt_hilo(x0, x1, ah, al);
        #pragma unroll
        for (int c = 0; c < 8; ++c) {
            bf16x8 bh = *reinterpret_cast<const bf16x8*>(W1h + (size_t)((c * 4 + s) * 64 + l) * 8);
            bf16x8 bl = *reinterpret_cast<const bf16x8*>(W1l + (size_t)((c * 4 + s) * 64 + l) * 8);
            acc[c] = MFMA16(al, bh, acc[c]);
            acc[c] = MFMA16(ah, bl, acc[c]);
            acc[c] = MFMA16(ah, bh, acc[c]);
        }
    }
    #pragma unroll
    for (int c = 0; c < 8; ++c) {
        #pragma unroll
        for (int i = 0; i < 4; ++i) {
            float yv = gelu_f(acc[c][i] + b1v[c]);
            Yh[(w * 16 + lg * 4 + i) * YLD + c * 16 + lr] = f2bf_rn(yv);
        }
    }

    #pragma unroll
    for (int c = 0; c < 8; ++c) acc[c] = (f32x4)(0.f);
    const ushort* yr = Yh + (w * 16 + lr) * YLD;
    #pragma unroll
    for (int s = 0; s < 4; ++s) {
        bf16x8 ah = *reinterpret_cast<const bf16x8*>(yr + s * 32 + lg * 8);
        #pragma unroll
        for (int c = 0; c < 8; ++c) {
            bf16x8 bh = *reinterpret_cast<const bf16x8*>(W2h + (size_t)((c * 4 + s) * 64 + l) * 8);
            bf16x8 bl = *reinterpret_cast<const bf16x8*>(W2l + (size_t)((c * 4 + s) * 64 + l) * 8);
            acc[c] = MFMA16(ah, bl, acc[c]);
            acc[c] = MFMA16(ah, bh, acc[c]);
        }
    }

    const int nrow = n0 + w * 16 + lg * 4;
    #pragma unroll
    for (int i = 0; i < 4; ++i) {
        if (nrow + i < NN) {
            #pragma unroll
            for (int c = 0; c < 8; ++c)
                msgN[(size_t)(nrow + i) * DD + c * 16 + lr] = f2bf_rn(gelu_f(acc[c][i] + b2v[c]));
        }
    }
}

// ---------------- fused kernel B: 16 nodes/block (3125 blocks, 256 thr) ----------------
// Phase 1: gather ordered BY NBR-SECTION (all blocks sweep sections in the same order ->
// each XCD's L2 holds the live 3.2 MB msgN slice; 15 of 16 row re-reads become L2 hits).
// Phase 2: node FFN column-split across 4 waves. NN = 3125*16 exactly -> no bounds checks.
__global__ __launch_bounds__(256, 8) void agg_node(
    const float* __restrict__ reps, const int* __restrict__ edges, const float* __restrict__ ew,
    const int* __restrict__ bucket, const int* __restrict__ cnt4,
    const int* __restrict__ spillCnt, const int* __restrict__ spill,
    const ushort* __restrict__ msgN,
    const ushort* __restrict__ U1h, const ushort* __restrict__ U1l, const float* __restrict__ C1,
    const ushort* __restrict__ U2h, const ushort* __restrict__ U2l, const float* __restrict__ C2,
    float* __restrict__ out)
{
    __shared__ ushort aggL[16 * YLD];
    __shared__ ushort Yh[16 * YLD];
    __shared__ float ssqP[4][16];
    const int t = threadIdx.x;
    const int n0 = blockIdx.x * 16;

    // ---- phase 1: 16 groups x 1 node, section-ordered gather ----
    {
        const int g = t >> 4, la = t & 15;
        const int node = n0 + g;
        const ushort* base = msgN + la * 8;
        float acc[8] = {0.f, 0.f, 0.f, 0.f, 0.f, 0.f, 0.f, 0.f};
        int4 c4 = *reinterpret_cast<const int4*>(&cnt4[node * SECN]);
        const int cv[4] = {c4.x, c4.y, c4.z, c4.w};
        bool hasSpill = (cv[0] > SEC_CAP) | (cv[1] > SEC_CAP) |
                        (cv[2] > SEC_CAP) | (cv[3] > SEC_CAP);
        const int* b = bucket + node * BSTR;
        #pragma unroll
        for (int sec = 0; sec < SECN; ++sec) {
            int sc = cv[sec] < SEC_CAP ? cv[sec] : SEC_CAP;
            const int* bs = b + sec * SEC_CAP;
            int k = 0;
            for (; k + 1 < sc; k += 2) {
                int e0 = bs[k], e1 = bs[k + 1];
                int q0 = edges[EE + e0], q1 = edges[EE + e1];
                float w0 = ew[e0], w1 = ew[e1];
                bf16x8 m0 = *reinterpret_cast<const bf16x8*>(base + (size_t)q0 * DD);
                bf16x8 m1 = *reinterpret_cast<const bf16x8*>(base + (size_t)q1 * DD);
                #pragma unroll
                for (int j = 0; j < 8; ++j) {
                    acc[j] = fmaf(w0, bf2f((ushort)m0[j]), acc[j]);
                    acc[j] = fmaf(w1, bf2f((ushort)m1[j]), acc[j]);
                }
            }
            if (k < sc) {
                int e0 = bs[k];
                int q0 = edges[EE + e0];
                float w0 = ew[e0];
                bf16x8 m0 = *reinterpret_cast<const bf16x8*>(base + (size_t)q0 * DD);
                #pragma unroll
                for (int j = 0; j < 8; ++j) acc[j] = fmaf(w0, bf2f((ushort)m0[j]), acc[j]);
            }
        }
        if (hasSpill) {                  // exact spill fold-in (near-empty here)
            int sc = spillCnt[0]; if (sc > SPILL_CAP) sc = SPILL_CAP;
            for (int i = 0; i < sc; ++i) {
                int eid = spill[i];
                if (edges[eid] == node) {
                    int q0 = edges[EE + eid];
                    float w0 = ew[eid];
                    bf16x8 m0 = *reinterpret_cast<const bf16x8*>(base + (size_t)q0 * DD);
                    #pragma unroll
                    for (int j = 0; j < 8; ++j)
                        acc[j] = fmaf(w0, bf2f((ushort)m0[j]), acc[j]);
                }
            }
        }
        uint4 o;
        o.x = pk2(acc[0], acc[1]);
        o.y = pk2(acc[2], acc[3]);
        o.z = pk2(acc[4], acc[5]);
        o.w = pk2(acc[6], acc[7]);
        *reinterpret_cast<uint4*>(&aggL[g * YLD + la * 8]) = o;
    }
    __syncthreads();

    // ---- phase 2: node FFN, wave w owns col tiles {2w, 2w+1} ----
    const int w = t >> 6, l = t & 63, lg = l >> 4, lr = l & 15;

    float c1v[2], c2v[2];
    #pragma unroll
    for (int cc = 0; cc < 2; ++cc) {
        c1v[cc] = C1[(2 * w + cc) * 16 + lr];
        c2v[cc] = C2[(2 * w + cc) * 16 + lr];
    }

    f32x4 acc[2];
    #pragma unroll
    for (int cc = 0; cc < 2; ++cc) acc[cc] = (f32x4)(0.f);

    // layer 1, reps half (k=0..127): f32 A hi+lo, 3 MFMAs
    #pragma unroll
    for (int s = 0; s < 4; ++s) {
        const float* sp = reps + (size_t)(n0 + lr) * DD + s * 32 + lg * 8;
        float4 x0 = *reinterpret_cast<const float4*>(sp);
        float4 x1 = *reinterpret_cast<const float4*>(sp + 4);
        bf16x8 ah, al;
        cvt_hilo(x0, x1, ah, al);
        #pragma unroll
        for (int cc = 0; cc < 2; ++cc) {
            int c = 2 * w + cc;
            bf16x8 bh = *reinterpret_cast<const bf16x8*>(U1h + (size_t)((c * 8 + s) * 64 + l) * 8);
            bf16x8 bl = *reinterpret_cast<const bf16x8*>(U1l + (size_t)((c * 8 + s) * 64 + l) * 8);
            acc[cc] = MFMA16(al, bh, acc[cc]);
            acc[cc] = MFMA16(ah, bl, acc[cc]);
            acc[cc] = MFMA16(ah, bh, acc[cc]);
        }
    }
    // layer 1, agg half (k=128..255): bf16 A from LDS, 2 MFMAs
    const ushort* ar = aggL + lr * YLD;
    #pragma unroll
    for (int s = 4; s < 8; ++s) {
        bf16x8 ah = *reinterpret_cast<const bf16x8*>(ar + (s - 4) * 32 + lg * 8);
        #pragma unroll
        for (int cc = 0; cc < 2; ++cc) {
            int c = 2 * w + cc;
            bf16x8 bh = *reinterpret_cast<const bf16x8*>(U1h + (size_t)((c * 8 + s) * 64 + l) * 8);
            bf16x8 bl = *reinterpret_cast<const bf16x8*>(U1l + (size_t)((c * 8 + s) * 64 + l) * 8);
            acc[cc] = MFMA16(ah, bl, acc[cc]);
            acc[cc] = MFMA16(ah, bh, acc[cc]);
        }
    }
    #pragma unroll
    for (int cc = 0; cc < 2; ++cc) {
        #pragma unroll
        for (int i = 0; i < 4; ++i) {
            float yv = gelu_f(acc[cc][i] + c1v[cc]);
            Yh[(lg * 4 + i) * YLD + (2 * w + cc) * 16 + lr] = f2bf_rn(yv);
        }
    }
    __syncthreads();   // Y rows assembled from all 4 waves' column slices

    // layer 2: K=128, A = full bf16 Y rows from LDS, 2 MFMAs
    #pragma unroll
    for (int cc = 0; cc < 2; ++cc) acc[cc] = (f32x4)(0.f);
    const ushort* yr2 = Yh + lr * YLD;
    #pragma unroll
    for (int s = 0; s < 4; ++s) {
        bf16x8 ah = *reinterpret_cast<const bf16x8*>(yr2 + s * 32 + lg * 8);
        #pragma unroll
        for (int cc = 0; cc < 2; ++cc) {
            int c = 2 * w + cc;
            bf16x8 bh = *reinterpret_cast<const bf16x8*>(U2h + (size_t)((c * 4 + s) * 64 + l) * 8);
            bf16x8 bl = *reinterpret_cast<const bf16x8*>(U2l + (size_t)((c * 4 + s) * 64 + l) * 8);
            acc[cc] = MFMA16(ah, bl, acc[cc]);
            acc[cc] = MFMA16(ah, bh, acc[cc]);
        }
    }

    // bias + GELU + 4-partial L2-norm
    float ssq[4] = {0.f, 0.f, 0.f, 0.f};
    #pragma unroll
    for (int cc = 0; cc < 2; ++cc) {
        #pragma unroll
        for (int i = 0; i < 4; ++i) {
            float vv = gelu_f(acc[cc][i] + c2v[cc]);
            acc[cc][i] = vv;
            ssq[i] = fmaf(vv, vv, ssq[i]);
        }
    }
    #pragma unroll
    for (int i = 0; i < 4; ++i) {
        #pragma unroll
        for (int msk = 1; msk < 16; msk <<= 1) ssq[i] += __shfl_xor(ssq[i], msk);
    }
    const int row0 = lg * 4;
    if (lr == 0) {
        #pragma unroll
        for (int i = 0; i < 4; ++i) ssqP[w][row0 + i] = ssq[i];
    }
    __syncthreads();
    #pragma unroll
    for (int i = 0; i < 4; ++i) {
        float tot = ssqP[0][row0 + i] + ssqP[1][row0 + i] +
                    ssqP[2][row0 + i] + ssqP[3][row0 + i];
        float sc = rsqrtf(fmaxf(tot, 1e-12f));
        #pragma unroll
        for (int cc = 0; cc < 2; ++cc)
            out[(size_t)(n0 + row0 + i) * DD + (2 * w + cc) * 16 + lr] = acc[cc][i] * sc;
    }
}

// ---------------- launch ----------------
extern "C" void kernel_launch(void* const* d_in, const int* in_sizes, int n_in,
                              void* d_out, int out_size, void* d_ws, size_t ws_size,
                              hipStream_t stream)
{
    const float* reps = (const float*)d_in[0];
    const int*   edges = (const int*)d_in[1];
    const float* ew   = (const float*)d_in[2];
    const float* bn1g = (const float*)d_in[3];
    const float* bn1b = (const float*)d_in[4];
    const float* bn1m = (const float*)d_in[5];
    const float* bn1v = (const float*)d_in[6];
    const float* w1   = (const float*)d_in[7];
    const float* b1   = (const float*)d_in[8];
    const float* bn2g = (const float*)d_in[9];
    const float* bn2b = (const float*)d_in[10];
    const float* bn2m = (const float*)d_in[11];
    const float* bn2v = (const float*)d_in[12];
    const float* w2   = (const float*)d_in[13];
    const float* b2   = (const float*)d_in[14];
    const float* ubn1g = (const float*)d_in[15];
    const float* ubn1b = (const float*)d_in[16];
    const float* ubn1m = (const float*)d_in[17];
    const float* ubn1v = (const float*)d_in[18];
    const float* u1    = (const float*)d_in[19];
    const float* ub1   = (const float*)d_in[20];
    const float* ubn2g = (const float*)d_in[21];
    const float* ubn2b = (const float*)d_in[22];
    const float* ubn2m = (const float*)d_in[23];
    const float* ubn2v = (const float*)d_in[24];
    const float* u2    = (const float*)d_in[25];
    const float* ub2   = (const float*)d_in[26];

    // workspace layout (bytes) — d_out used ONLY for final output
    char* wsb = (char*)d_ws;
    ushort* msgN     = (ushort*)wsb;                     // 12,800,000 B
    int*    bucket   = (int*)(wsb + 12800000);           // NN*BSTR*4 = 9,600,000 B
    int*    cnt4     = (int*)(wsb + 22400000);           // NN*4*4 = 800,000 B
    int*    spillCnt = (int*)(wsb + 23200000);           // 4 B (+pad)
    int*    spill    = (int*)(wsb + 23200016);           // 400,000 B
    float*  B1f      = (float*)(wsb + 23600016);         // 128 f32 each, 16B aligned
    float*  B2f = B1f + 128;
    float*  C1f = B2f + 128;
    float*  C2f = C1f + 128;
    ushort* up  = (ushort*)(C2f + 128);
    ushort* W1h = up;                                    // 16384 each
    ushort* W1l = W1h + 16384;
    ushort* W2h = W1l + 16384;
    ushort* W2l = W2h + 16384;
    ushort* U1h = W2l + 16384;                           // 32768 each
    ushort* U1l = U1h + 32768;
    ushort* U2h = U1l + 32768;                           // 16384 each
    ushort* U2l = U2h + 16384;
    if (ws_size < 23950000) return;

    init_bias<<<1, 128, 0, stream>>>(b1, b2, ub1, ub2, B1f, B2f, C1f, C2f);
    pack_all<<<320, 256, 0, stream>>>(w1, bn1g, bn1v, W1h, W1l,
                                      w2, bn2g, bn2v, W2h, W2l,
                                      u1, ubn1g, ubn1v, U1h, U1l,
                                      u2, ubn2g, ubn2v, U2h, U2l);
    fold_all<<<20, 256, 0, stream>>>(w1, bn1g, bn1b, bn1m, bn1v, B1f,
                                     w2, bn2g, bn2b, bn2m, bn2v, B2f,
                                     u1, ubn1g, ubn1b, ubn1m, ubn1v, C1f,
                                     u2, ubn2g, ubn2b, ubn2m, ubn2v, C2f,
                                     cnt4, spillCnt);

    prep_fill<<<FILLB + 392, 512, 0, stream>>>(reps, edges, W1h, W1l, B1f,
                                               W2h, W2l, B2f, msgN,
                                               cnt4, spillCnt, spill, bucket);
    agg_node<<<NN / 16, 256, 0, stream>>>(reps, edges, ew, bucket, cnt4,
                                          spillCnt, spill, msgN,
                                          U1h, U1l, C1f, U2h, U2l, C2f,
                                          (float*)d_out);
}